// Round 1
// baseline (285.901 us; speedup 1.0000x reference)
//
#include <hip/hip_runtime.h>
#include <math.h>

// Problem constants (mask is all-true 160x160 -> nv=nh=10, fixed)
#define CPS 16
#define ENC 128
#define NH 10
#define NPATCH 100      // patches per batch image
#define BATCH 4
#define CCH 256         // input channels
#define WIDTH 160
#define HW 25600        // 160*160
#define ROWS_TOTAL 400  // BATCH*NPATCH

// ---------------------------------------------------------------------------
// K1: 1x1 conv (256ch -> 1) + bias + ReLU, scattered into patch-flat layout
// xr[branch][patch][j]  j = (h%16)*16 + (w%16), patch = b*100 + (h/16)*10 + w/16
// One thread = 2 horizontally-adjacent pixels (float2), serial loop over 256 ch.
// branch/b derived from blockIdx only => weight loads are wave-uniform (s_load).
// ---------------------------------------------------------------------------
__global__ __launch_bounds__(64) void conv_relu_kernel(
    const float* __restrict__ f1, const float* __restrict__ f2,
    const float* __restrict__ wci, const float* __restrict__ bci,
    const float* __restrict__ wcd, const float* __restrict__ bcd,
    float* __restrict__ xr)
{
    int tid   = threadIdx.x;
    int plane = blockIdx.x / 200;        // 0..7  (branch*4 + b), uniform
    int wb    = blockIdx.x % 200;
    int branch = plane >> 2;
    int b      = plane & 3;

    const float* f    = branch ? f2  : f1;
    const float* wsel = branch ? wcd : wci;   // scalar (uniform) pointer
    float bias        = branch ? bcd[0] : bci[0];

    int pp  = wb * 64 + tid;             // pixel-pair index within plane
    int pix = pp * 2;

    const float* fbase = f + (size_t)b * CCH * HW + pix;
    float2 acc = make_float2(0.f, 0.f);
    #pragma unroll 8
    for (int c = 0; c < CCH; ++c) {
        float2 v = *(const float2*)(fbase + (size_t)c * HW);
        float wc = wsel[c];              // uniform -> scalar load
        acc.x = fmaf(v.x, wc, acc.x);
        acc.y = fmaf(v.y, wc, acc.y);
    }
    acc.x = fmaxf(acc.x + bias, 0.f);
    acc.y = fmaxf(acc.y + bias, 0.f);

    int h = pix / WIDTH, w = pix % WIDTH;        // both pixels share h, patch
    int p = b * NPATCH + (h >> 4) * NH + (w >> 4);
    int j = (h & 15) * CPS + (w & 15);           // j even -> float2 aligned
    *(float2*)(xr + ((size_t)(branch * ROWS_TOTAL + p)) * 256 + j) = acc;
}

// ---------------------------------------------------------------------------
// K2: per-row MLP (256 -> relu(w1) 256 -> w2 128) + LayerNorm.
// 4 rows per block, 256 threads. w1/w2 streamed from L2.
// ---------------------------------------------------------------------------
__global__ __launch_bounds__(256) void mlp_ln_kernel(
    const float* __restrict__ xr,
    const float* __restrict__ w1i, const float* __restrict__ w2i,
    const float* __restrict__ gi,  const float* __restrict__ bli,
    const float* __restrict__ w1d, const float* __restrict__ w2d,
    const float* __restrict__ gd,  const float* __restrict__ bld,
    float* __restrict__ e)
{
    const int R = 4;
    __shared__ float xs[R][256];
    __shared__ float ys[R][256];
    __shared__ float zs[R][ENC];

    int tid    = threadIdx.x;
    int branch = blockIdx.x / 100;            // uniform
    int row0   = (blockIdx.x % 100) * R;

    const float* w1 = branch ? w1d : w1i;
    const float* w2 = branch ? w2d : w2i;
    const float* g  = branch ? gd  : gi;
    const float* bl = branch ? bld : bli;

    #pragma unroll
    for (int r = 0; r < R; ++r)
        xs[r][tid] = xr[((size_t)(branch * ROWS_TOTAL + row0 + r)) * 256 + tid];
    __syncthreads();

    // GEMM1: y[r][tid] = relu(dot(xs[r], w1[tid,:]))
    {
        float acc[R] = {0.f, 0.f, 0.f, 0.f};
        const float4* w1r = (const float4*)(w1 + (size_t)tid * 256);
        #pragma unroll 4
        for (int c4 = 0; c4 < 64; ++c4) {
            float4 wv = w1r[c4];
            #pragma unroll
            for (int r = 0; r < R; ++r) {
                float4 xv = *(const float4*)(&xs[r][c4 * 4]);   // LDS broadcast
                acc[r] = fmaf(xv.x, wv.x, acc[r]);
                acc[r] = fmaf(xv.y, wv.y, acc[r]);
                acc[r] = fmaf(xv.z, wv.z, acc[r]);
                acc[r] = fmaf(xv.w, wv.w, acc[r]);
            }
        }
        #pragma unroll
        for (int r = 0; r < R; ++r) ys[r][tid] = fmaxf(acc[r], 0.f);
    }
    __syncthreads();

    // GEMM2: z[r][m] = dot(ys[r], w2[m,:])  (512 outputs, 2 per thread)
    #pragma unroll
    for (int i = 0; i < 2; ++i) {
        int idx = tid + 256 * i;
        int r = idx >> 7, m = idx & 127;
        float acc = 0.f;
        const float4* w2r = (const float4*)(w2 + (size_t)m * 256);
        #pragma unroll 4
        for (int c4 = 0; c4 < 64; ++c4) {
            float4 wv = w2r[c4];
            float4 yv = *(const float4*)(&ys[r][c4 * 4]);       // LDS broadcast
            acc = fmaf(yv.x, wv.x, acc);
            acc = fmaf(yv.y, wv.y, acc);
            acc = fmaf(yv.z, wv.z, acc);
            acc = fmaf(yv.w, wv.w, acc);
        }
        zs[r][m] = acc;
    }
    __syncthreads();

    // LayerNorm: wave r handles row r (each lane owns 2 of 128 elements)
    int r = tid >> 6, lane = tid & 63;
    float a  = zs[r][lane];
    float b2 = zs[r][lane + 64];
    float s = a + b2;
    float q = a * a + b2 * b2;
    #pragma unroll
    for (int off = 32; off >= 1; off >>= 1) {
        s += __shfl_xor(s, off);
        q += __shfl_xor(q, off);
    }
    float mu  = s * (1.f / 128.f);
    float var = q * (1.f / 128.f) - mu * mu;
    float inv = 1.f / sqrtf(var + 1e-5f);
    float* erow = e + ((size_t)(branch * ROWS_TOTAL + row0 + r)) * ENC;
    erow[lane]      = (a  - mu) * inv * g[lane]      + bl[lane];
    erow[lane + 64] = (b2 - mu) * inv * g[lane + 64] + bl[lane + 64];
}

// ---------------------------------------------------------------------------
// K3: logits = scale * e1[b] @ e2[b]^T  (4 x 100 x 100) + transposed copy
// ---------------------------------------------------------------------------
__global__ __launch_bounds__(256) void logits_kernel(
    const float* __restrict__ e, const float* __restrict__ lsc,
    float* __restrict__ out)
{
    int gidx = blockIdx.x * 256 + threadIdx.x;
    if (gidx >= BATCH * NPATCH * NPATCH) return;
    float scale = expf(lsc[0]);

    int b    = gidx / (NPATCH * NPATCH);
    int rrem = gidx % (NPATCH * NPATCH);
    int n = rrem / NPATCH, m = rrem % NPATCH;

    const float4* e1 = (const float4*)(e + (size_t)(b * NPATCH + n) * ENC);
    const float4* e2 = (const float4*)(e + (size_t)(ROWS_TOTAL + b * NPATCH + m) * ENC);
    float acc = 0.f;
    #pragma unroll 8
    for (int c4 = 0; c4 < ENC / 4; ++c4) {
        float4 av = e1[c4], bv = e2[c4];
        acc = fmaf(av.x, bv.x, acc);
        acc = fmaf(av.y, bv.y, acc);
        acc = fmaf(av.z, bv.z, acc);
        acc = fmaf(av.w, bv.w, acc);
    }
    float L = scale * acc;
    out[gidx] = L;                                              // logits_per_img
    out[BATCH * NPATCH * NPATCH + b * NPATCH * NPATCH + m * NPATCH + n] = L; // transposed
}

extern "C" void kernel_launch(void* const* d_in, const int* in_sizes, int n_in,
                              void* d_out, int out_size, void* d_ws, size_t ws_size,
                              hipStream_t stream) {
    const float* f1  = (const float*)d_in[0];
    const float* f2  = (const float*)d_in[1];
    // d_in[2] = mask_c1 (all true -> nv=nh=10 hardcoded)
    const float* wci = (const float*)d_in[3];
    const float* bci = (const float*)d_in[4];
    const float* w1i = (const float*)d_in[5];
    const float* w2i = (const float*)d_in[6];
    const float* gi  = (const float*)d_in[7];
    const float* bli = (const float*)d_in[8];
    const float* wcd = (const float*)d_in[9];
    const float* bcd = (const float*)d_in[10];
    const float* w1d = (const float*)d_in[11];
    const float* w2d = (const float*)d_in[12];
    const float* gd  = (const float*)d_in[13];
    const float* bld = (const float*)d_in[14];
    const float* lsc = (const float*)d_in[15];

    float* xr = (float*)d_ws;                  // 2*400*256 floats = 800 KB
    float* e  = xr + 2 * ROWS_TOTAL * 256;     // 2*400*128 floats = 400 KB
    float* out = (float*)d_out;

    // K1: 8 planes * 200 blocks, 64 threads each (fine-grained for load balance)
    conv_relu_kernel<<<1600, 64, 0, stream>>>(f1, f2, wci, bci, wcd, bcd, xr);
    // K2: 2 branches * 100 row-groups of 4
    mlp_ln_kernel<<<200, 256, 0, stream>>>(xr, w1i, w2i, gi, bli,
                                           w1d, w2d, gd, bld, e);
    // K3: 40000 (b,n,m) triples
    logits_kernel<<<(BATCH * NPATCH * NPATCH + 255) / 256, 256, 0, stream>>>(e, lsc, out);
}